// Round 2
// baseline (4037.029 us; speedup 1.0000x reference)
//
#include <hip/hip_runtime.h>

// ---------------------------------------------------------------------------
// BiLSTM tagger: emb -> [fwd LSTM, batch-flipped copy] x2 -> FC -> log_softmax
// B=64, T=256, V=50000, E=256, H=512, O=50. Gate dim G=4H=2048.
// Workspace budget ~115 MB (bf16 intermediates, aliased/fused buffers).
// ---------------------------------------------------------------------------

#define B_ 64
#define T_ 256
#define E_ 256
#define H_ 512
#define G_ 2048
#define O_ 50
#define NROW (B_ * T_)   // 16384

typedef unsigned short u16;
typedef unsigned int u32;
typedef unsigned long long u64;
typedef short bf16x8 __attribute__((ext_vector_type(8)));
typedef u16 u16x4 __attribute__((ext_vector_type(4)));
typedef float f32x4 __attribute__((ext_vector_type(4)));

__device__ __forceinline__ u16 f2bf(float f) {
    unsigned u = __float_as_uint(f);
    return (u16)((u + 0x7fffu + ((u >> 16) & 1u)) >> 16);
}
__device__ __forceinline__ float bf2f(u16 x) {
    return __uint_as_float(((u32)x) << 16);
}
__device__ __forceinline__ float sigm(float x) {
    x = fminf(fmaxf(x, -30.f), 30.f);
    return 1.f / (1.f + __expf(-x));
}
__device__ __forceinline__ float tanh_f(float x) {
    x = fminf(fmaxf(x, -15.f), 15.f);
    float e = __expf(2.f * x);
    return (e - 1.f) / (e + 1.f);
}

// --------------------------- small prep kernels ----------------------------

__global__ __launch_bounds__(256) void f32_to_bf16_vec(
    const float* __restrict__ in, u16* __restrict__ out, int n4)
{
    int i = blockIdx.x * 256 + threadIdx.x;
    if (i >= n4) return;
    float4 v = *(const float4*)&in[(size_t)i * 4];
    u16x4 o = { f2bf(v.x), f2bf(v.y), f2bf(v.z), f2bf(v.w) };
    *(u16x4*)&out[(size_t)i * 4] = o;
}

// A1[r][e] = bf16(emb[x[r]][e]); one thread per 4 elems.
__global__ __launch_bounds__(256) void embed_to_bf16(
    const int* __restrict__ x, const float* __restrict__ emb, u16* __restrict__ A1)
{
    int i = blockIdx.x * 256 + threadIdx.x;     // < 1048576
    int r = i >> 6, c4 = (i & 63) * 4;
    int xi = x[r];
    float4 v = *(const float4*)&emb[(size_t)xi * E_ + c4];
    u16x4 o = { f2bf(v.x), f2bf(v.y), f2bf(v.z), f2bf(v.w) };
    *(u16x4*)&A1[(size_t)r * E_ + c4] = o;
}

// ------------------------------- bf16 GEMM ---------------------------------
// C[M,N] = A[M,K] @ B[N,K]^T + bias[N]; A,B bf16, C bf16 (fp32 accum).
// FLIP mode: A is h1b (M x 512); logical A row r = [h1b[r], h1b[flip(r)]]
// (flip on batch dim: r = b*256+t -> (63-b)*256+t), K must be 1024.
template<bool FLIP>
__global__ __launch_bounds__(256) void gemm_bf16(
    const u16* __restrict__ A, const u16* __restrict__ Bw,
    const float* __restrict__ bias, u16* __restrict__ C,
    int M, int N, int K)
{
    __shared__ u16 Asm[128][40];   // +8 pad: 2-way max on frag reads (free)
    __shared__ u16 Bsm[128][40];
    const int tid = threadIdx.x, lane = tid & 63, wave = tid >> 6;
    const int wr = wave >> 1, wc = wave & 1;
    const int bm = blockIdx.y, bn = blockIdx.x;
    f32x4 acc[4][4] = {};
    const int r = tid >> 1, kc = (tid & 1) * 16;
    const int grow = bm * 128 + r;
    int frow = 0;
    if (FLIP) { int b = grow >> 8, t = grow & 255; frow = (63 - b) * 256 + t; }
    const u16* bg = Bw + (size_t)(bn * 128 + r) * K;
    for (int k0 = 0; k0 < K; k0 += 32) {
        int col = k0 + kc;
        const u16* asrc;
        if (FLIP)
            asrc = (col < 512) ? A + (size_t)grow * 512 + col
                               : A + (size_t)frow * 512 + (col - 512);
        else
            asrc = A + (size_t)grow * K + col;
        __syncthreads();
        *(int4*)&Asm[r][kc]     = *(const int4*)asrc;
        *(int4*)&Asm[r][kc + 8] = *(const int4*)(asrc + 8);
        *(int4*)&Bsm[r][kc]     = *(const int4*)(bg + col);
        *(int4*)&Bsm[r][kc + 8] = *(const int4*)(bg + col + 8);
        __syncthreads();
        bf16x8 af[4], bf[4];
        #pragma unroll
        for (int mt = 0; mt < 4; mt++)
            af[mt] = *(const bf16x8*)&Asm[wr * 64 + mt * 16 + (lane & 15)][(lane >> 4) * 8];
        #pragma unroll
        for (int nt = 0; nt < 4; nt++)
            bf[nt] = *(const bf16x8*)&Bsm[wc * 64 + nt * 16 + (lane & 15)][(lane >> 4) * 8];
        #pragma unroll
        for (int mt = 0; mt < 4; mt++)
            #pragma unroll
            for (int nt = 0; nt < 4; nt++)
                acc[mt][nt] = __builtin_amdgcn_mfma_f32_16x16x32_bf16(
                    af[mt], bf[nt], acc[mt][nt], 0, 0, 0);
    }
    #pragma unroll
    for (int mt = 0; mt < 4; mt++) {
        #pragma unroll
        for (int nt = 0; nt < 4; nt++) {
            int col = bn * 128 + wc * 64 + nt * 16 + (lane & 15);
            float bv = bias[col];
            #pragma unroll
            for (int rr = 0; rr < 4; rr++) {
                int row = bm * 128 + wr * 64 + mt * 16 + (lane >> 4) * 4 + rr;
                C[(size_t)row * N + col] = f2bf(acc[mt][nt][rr] + bv);
            }
        }
    }
}

// ------------------------------- LSTM scan ---------------------------------
// Persistent kernel: 128 wgs x 256 threads, all co-resident (<=256 CUs).
// wg = (bmg 0..3: 16-batch tile, un 0..31: 16-unit tile). Wave w owns gate w.
// W_hh fragments in 64 VGPRs. h exchanged via global bf16 double buffer with
// AGENT-scope atomics; per-(step,bmg) release-counter; tid0 acquire-spin.
__global__ __launch_bounds__(256, 1) void lstm_scan(
    const u16* __restrict__ xg,     // (B,T,G) bf16
    const float* __restrict__ Whh,  // (G,H) fp32
    const float* __restrict__ h0, const float* __restrict__ c0,   // (B,H)
    u16* __restrict__ hout,         // (B,T,H) bf16
    u16* hx,                        // (2,B,H) bf16 double buffer
    int* cnt)                       // (T_+1, 4) release counters, zeroed
{
    __shared__ u16 hl[16][520];       // h tile, padded stride (2-way = free)
    __shared__ float glds[4][16][17];
    const int tid = threadIdx.x, lane = tid & 63, wave = tid >> 6;
    const int wg = blockIdx.x, bmg = wg >> 5, un = wg & 31;

    // Preload W_hh B-fragments: gate=wave, unit col = un*16+(lane&15),
    // k-chunk base = (lane>>4)*8; 16 chunks of K=32.
    bf16x8 breg[16];
    {
        const float* wr0 = Whh + (size_t)(wave * H_ + un * 16 + (lane & 15)) * H_
                           + ((lane >> 4) * 8);
        #pragma unroll
        for (int kk = 0; kk < 16; kk++) {
            float4 v0 = *(const float4*)(wr0 + kk * 32);
            float4 v1 = *(const float4*)(wr0 + kk * 32 + 4);
            bf16x8 bb;
            bb[0] = (short)f2bf(v0.x); bb[1] = (short)f2bf(v0.y);
            bb[2] = (short)f2bf(v0.z); bb[3] = (short)f2bf(v0.w);
            bb[4] = (short)f2bf(v1.x); bb[5] = (short)f2bf(v1.y);
            bb[6] = (short)f2bf(v1.z); bb[7] = (short)f2bf(v1.w);
            breg[kk] = bb;
        }
    }

    const int bb_ = tid >> 4, uu = tid & 15;
    const int brow = bmg * 16 + bb_, ucol = un * 16 + uu;
    float c = c0[brow * H_ + ucol];
    {   // publish h0 slice into buffer 0 (packed u32, agent atomics)
        u32 me = f2bf(h0[brow * H_ + ucol]);
        u32 ot = (u32)__shfl_xor((int)me, 1);
        if (!(uu & 1))
            __hip_atomic_store((u32*)(hx + (size_t)brow * H_ + ucol), me | (ot << 16),
                               __ATOMIC_RELAXED, __HIP_MEMORY_SCOPE_AGENT);
    }
    __syncthreads();
    if (tid == 0)
        __hip_atomic_fetch_add(&cnt[0 * 4 + bmg], 1,
                               __ATOMIC_RELEASE, __HIP_MEMORY_SCOPE_AGENT);

    bool gaveup = false;
    #pragma unroll 1
    for (int t = 0; t < T_; ++t) {
        // wait: all 32 wgs of my batch group published h_t
        if (tid == 0 && !gaveup) {
            int it = 0;
            while (__hip_atomic_load(&cnt[t * 4 + bmg],
                                     __ATOMIC_ACQUIRE, __HIP_MEMORY_SCOPE_AGENT) < 32) {
                __builtin_amdgcn_s_sleep(1);
                if (++it > (1 << 20)) { gaveup = true; break; }  // never wedge
            }
        }
        __syncthreads();

        // cooperative load of the 16x512 h_t tile into LDS (agent atomics)
        const u16* hsrc = hx + (size_t)(t & 1) * (B_ * H_) + (size_t)bmg * 16 * H_;
        #pragma unroll
        for (int j = 0; j < 8; ++j) {
            int idx = tid + j * 256;            // 0..2047 u64 slots
            int row = idx >> 7, c4 = idx & 127; // 128 u64 per row
            u64 v = __hip_atomic_load((u64*)(hsrc + (size_t)row * H_ + c4 * 4),
                                      __ATOMIC_RELAXED, __HIP_MEMORY_SCOPE_AGENT);
            *(u64*)&hl[row][c4 * 4] = v;
        }
        __syncthreads();

        // gates = h_t @ Whh^T (this wave's gate tile), 2 accs for ILP
        f32x4 acc0 = {0.f,0.f,0.f,0.f}, acc1 = {0.f,0.f,0.f,0.f};
        const int ar = lane & 15, ac = (lane >> 4) * 8;
        #pragma unroll
        for (int kk = 0; kk < 16; kk += 2) {
            bf16x8 a0 = *(const bf16x8*)&hl[ar][ac + kk * 32];
            bf16x8 a1 = *(const bf16x8*)&hl[ar][ac + (kk + 1) * 32];
            acc0 = __builtin_amdgcn_mfma_f32_16x16x32_bf16(a0, breg[kk],     acc0, 0, 0, 0);
            acc1 = __builtin_amdgcn_mfma_f32_16x16x32_bf16(a1, breg[kk + 1], acc1, 0, 0, 0);
        }
        #pragma unroll
        for (int rr = 0; rr < 4; rr++)
            glds[wave][(lane >> 4) * 4 + rr][lane & 15] = acc0[rr] + acc1[rr];
        __syncthreads();

        // elementwise cell update; thread owns (batch bb_, unit uu)
        const size_t xb = ((size_t)brow * T_ + t) * G_ + un * 16 + uu;
        float ip = glds[0][bb_][uu] + bf2f(xg[xb]);
        float fp = glds[1][bb_][uu] + bf2f(xg[xb + 512]);
        float gp = glds[2][bb_][uu] + bf2f(xg[xb + 1024]);
        float op = glds[3][bb_][uu] + bf2f(xg[xb + 1536]);
        float gi = sigm(ip), gf = sigm(fp), gc = tanh_f(gp), go = sigm(op);
        c = gf * c + gi * gc;
        float h = go * tanh_f(c);
        u32 me = f2bf(h);
        hout[((size_t)brow * T_ + t) * H_ + ucol] = (u16)me;
        u32 ot = (u32)__shfl_xor((int)me, 1);
        if (!(uu & 1))
            __hip_atomic_store((u32*)(hx + (size_t)((t + 1) & 1) * (B_ * H_)
                                      + (size_t)brow * H_ + ucol),
                               me | (ot << 16),
                               __ATOMIC_RELAXED, __HIP_MEMORY_SCOPE_AGENT);
        __syncthreads();   // drains vmcnt: all stores done before release
        if (tid == 0)
            __hip_atomic_fetch_add(&cnt[(t + 1) * 4 + bmg], 1,
                                   __ATOMIC_RELEASE, __HIP_MEMORY_SCOPE_AGENT);
    }
}

// --------------------------- FC + log_softmax ------------------------------
// Block = 256 thr = 4 waves, 16 rows/block (same b). Stage [h2[r],h2[fr]]
// rows in LDS; lane o computes logit o; wave-shfl max/sum for log_softmax.
__global__ __launch_bounds__(256) void fc_logsoftmax(
    const u16* __restrict__ h2, const u16* __restrict__ Wfcb,
    const float* __restrict__ bfc, float* __restrict__ out)
{
    __shared__ u16 hl[16][1032];
    const int tid = threadIdx.x, lane = tid & 63, wave = tid >> 6;
    const int r0 = blockIdx.x * 16;
    const int b = r0 >> 8;
    const int fr0 = (63 - b) * T_ + (r0 & 255);
    #pragma unroll
    for (int j = 0; j < 16; ++j) {
        int idx = tid + j * 256;            // 0..4095 u64 slots
        int row = idx >> 8, c4 = idx & 255; // 256 u64 per row
        const u16* src = (c4 < 128)
            ? h2 + (size_t)(r0 + row) * H_ + c4 * 4
            : h2 + (size_t)(fr0 + row) * H_ + (c4 - 128) * 4;
        *(u64*)&hl[row][c4 * 4] = *(const u64*)src;
    }
    __syncthreads();
    for (int rr = wave * 4; rr < wave * 4 + 4; ++rr) {
        float acc = -1e30f;
        if (lane < O_) {
            const u16* w = Wfcb + (size_t)lane * 1024;
            float s = 0.f;
            for (int k = 0; k < 1024; k += 8) {
                bf16x8 wv = *(const bf16x8*)(w + k);
                bf16x8 hv = *(const bf16x8*)&hl[rr][k];   // broadcast read
                #pragma unroll
                for (int e = 0; e < 8; e++)
                    s += bf2f((u16)hv[e]) * bf2f((u16)wv[e]);
            }
            acc = s + bfc[lane];
        }
        float m = acc;
        #pragma unroll
        for (int off = 32; off > 0; off >>= 1) m = fmaxf(m, __shfl_xor(m, off));
        float e = (lane < O_) ? __expf(acc - m) : 0.f;
        float sm = e;
        #pragma unroll
        for (int off = 32; off > 0; off >>= 1) sm += __shfl_xor(sm, off);
        float lse = m + __logf(sm);
        if (lane < O_) out[(size_t)(r0 + rr) * O_ + lane] = acc - lse;
    }
}

// ------------------------------ launcher -----------------------------------

extern "C" void kernel_launch(void* const* d_in, const int* in_sizes, int n_in,
                              void* d_out, int out_size, void* d_ws, size_t ws_size,
                              hipStream_t stream)
{
    (void)in_sizes; (void)n_in; (void)out_size;
    const int*   x    = (const int*)  d_in[0];
    const float* emb  = (const float*)d_in[1];
    const float* Wih1 = (const float*)d_in[2];
    const float* Whh1 = (const float*)d_in[3];
    const float* b1   = (const float*)d_in[4];
    const float* h01  = (const float*)d_in[5];
    const float* c01  = (const float*)d_in[6];
    const float* Wih2 = (const float*)d_in[7];
    const float* Whh2 = (const float*)d_in[8];
    const float* b2   = (const float*)d_in[9];
    const float* h02  = (const float*)d_in[10];
    const float* c02  = (const float*)d_in[11];
    const float* Wfc  = (const float*)d_in[12];
    const float* bfc  = (const float*)d_in[13];
    float* out = (float*)d_out;

    char* ws = (char*)d_ws;
    size_t off = 0;
    auto alloc = [&](size_t bytes) {
        char* p = ws + off; off += (bytes + 255) & ~(size_t)255; return p;
    };
    u16* A1   = (u16*)alloc((size_t)NROW * E_ * 2);     //  8.39 MB
    u16* Wb1  = (u16*)alloc((size_t)G_ * E_ * 2);       //  1.05 MB
    u16* Wb2  = (u16*)alloc((size_t)G_ * 1024 * 2);     //  4.19 MB
    u16* Wfcb = (u16*)alloc((size_t)O_ * 1024 * 2);     //  0.10 MB
    u16* xgb  = (u16*)alloc((size_t)NROW * G_ * 2);     // 67.11 MB (L1+L2 share)
    u16* h1b  = (u16*)alloc((size_t)NROW * H_ * 2);     // 16.78 MB
    u16* h2b  = (u16*)alloc((size_t)NROW * H_ * 2);     // 16.78 MB
    u16* hx   = (u16*)alloc((size_t)2 * B_ * H_ * 2);   //  0.13 MB
    int* cnt  = (int*)alloc((size_t)2 * (T_ + 1) * 4 * sizeof(int));
    if (off > ws_size) return;   // clean diagnostic failure, never OOB

    hipMemsetAsync(cnt, 0, 2 * (T_ + 1) * 4 * sizeof(int), stream);
    f32_to_bf16_vec<<<(G_ * E_ / 4 + 255) / 256, 256, 0, stream>>>(Wih1, Wb1, G_ * E_ / 4);
    f32_to_bf16_vec<<<(G_ * 1024 / 4 + 255) / 256, 256, 0, stream>>>(Wih2, Wb2, G_ * 1024 / 4);
    f32_to_bf16_vec<<<(O_ * 1024 / 4 + 255) / 256, 256, 0, stream>>>(Wfc, Wfcb, O_ * 1024 / 4);
    embed_to_bf16<<<NROW * E_ / 4 / 256, 256, 0, stream>>>(x, emb, A1);

    gemm_bf16<false><<<dim3(G_ / 128, NROW / 128), 256, 0, stream>>>(
        A1, Wb1, b1, xgb, NROW, G_, E_);
    lstm_scan<<<128, 256, 0, stream>>>(xgb, Whh1, h01, c01, h1b, hx, cnt);

    gemm_bf16<true><<<dim3(G_ / 128, NROW / 128), 256, 0, stream>>>(
        h1b, Wb2, b2, xgb, NROW, G_, 1024);
    lstm_scan<<<128, 256, 0, stream>>>(xgb, Whh2, h02, c02, h2b, hx, cnt + (T_ + 1) * 4);

    fc_logsoftmax<<<NROW / 16, 256, 0, stream>>>(h2b, Wfcb, bfc, out);
}

// Round 3
// 2560.074 us; speedup vs baseline: 1.5769x; 1.5769x over previous
//
#include <hip/hip_runtime.h>

// ---------------------------------------------------------------------------
// BiLSTM tagger: emb -> [fwd LSTM, batch-flipped copy] x2 -> FC -> log_softmax
// B=64, T=256, V=50000, E=256, H=512, O=50. Gate dim G=4H=2048.
// Scan sync: per-wg release flags (no RMW), fan-in 8, xg prefetch.
// ---------------------------------------------------------------------------

#define B_ 64
#define T_ 256
#define E_ 256
#define H_ 512
#define G_ 2048
#define O_ 50
#define NROW (B_ * T_)   // 16384

typedef unsigned short u16;
typedef unsigned int u32;
typedef unsigned long long u64;
typedef short bf16x8 __attribute__((ext_vector_type(8)));
typedef u16 u16x4 __attribute__((ext_vector_type(4)));
typedef float f32x4 __attribute__((ext_vector_type(4)));

__device__ __forceinline__ u16 f2bf(float f) {
    unsigned u = __float_as_uint(f);
    return (u16)((u + 0x7fffu + ((u >> 16) & 1u)) >> 16);
}
__device__ __forceinline__ float bf2f(u16 x) {
    return __uint_as_float(((u32)x) << 16);
}
__device__ __forceinline__ float sigm(float x) {
    x = fminf(fmaxf(x, -30.f), 30.f);
    return 1.f / (1.f + __expf(-x));
}
__device__ __forceinline__ float tanh_f(float x) {
    x = fminf(fmaxf(x, -15.f), 15.f);
    float e = __expf(2.f * x);
    return (e - 1.f) / (e + 1.f);
}

// --------------------------- small prep kernels ----------------------------

__global__ __launch_bounds__(256) void f32_to_bf16_vec(
    const float* __restrict__ in, u16* __restrict__ out, int n4)
{
    int i = blockIdx.x * 256 + threadIdx.x;
    if (i >= n4) return;
    float4 v = *(const float4*)&in[(size_t)i * 4];
    u16x4 o = { f2bf(v.x), f2bf(v.y), f2bf(v.z), f2bf(v.w) };
    *(u16x4*)&out[(size_t)i * 4] = o;
}

// A1[r][e] = bf16(emb[x[r]][e]); one thread per 4 elems.
__global__ __launch_bounds__(256) void embed_to_bf16(
    const int* __restrict__ x, const float* __restrict__ emb, u16* __restrict__ A1)
{
    int i = blockIdx.x * 256 + threadIdx.x;     // < 1048576
    int r = i >> 6, c4 = (i & 63) * 4;
    int xi = x[r];
    float4 v = *(const float4*)&emb[(size_t)xi * E_ + c4];
    u16x4 o = { f2bf(v.x), f2bf(v.y), f2bf(v.z), f2bf(v.w) };
    *(u16x4*)&A1[(size_t)r * E_ + c4] = o;
}

// ------------------------------- bf16 GEMM ---------------------------------
// C[M,N] = A[M,K] @ B[N,K]^T + bias[N]; A,B bf16, C bf16 (fp32 accum).
// FLIP mode: A is h1b (M x 512); logical A row r = [h1b[r], h1b[flip(r)]]
// (flip on batch dim: r = b*256+t -> (63-b)*256+t), K must be 1024.
template<bool FLIP>
__global__ __launch_bounds__(256) void gemm_bf16(
    const u16* __restrict__ A, const u16* __restrict__ Bw,
    const float* __restrict__ bias, u16* __restrict__ C,
    int M, int N, int K)
{
    __shared__ u16 Asm[128][40];   // +8 pad: 2-way max on frag reads (free)
    __shared__ u16 Bsm[128][40];
    const int tid = threadIdx.x, lane = tid & 63, wave = tid >> 6;
    const int wr = wave >> 1, wc = wave & 1;
    const int bm = blockIdx.y, bn = blockIdx.x;
    f32x4 acc[4][4] = {};
    const int r = tid >> 1, kc = (tid & 1) * 16;
    const int grow = bm * 128 + r;
    int frow = 0;
    if (FLIP) { int b = grow >> 8, t = grow & 255; frow = (63 - b) * 256 + t; }
    const u16* bg = Bw + (size_t)(bn * 128 + r) * K;
    for (int k0 = 0; k0 < K; k0 += 32) {
        int col = k0 + kc;
        const u16* asrc;
        if (FLIP)
            asrc = (col < 512) ? A + (size_t)grow * 512 + col
                               : A + (size_t)frow * 512 + (col - 512);
        else
            asrc = A + (size_t)grow * K + col;
        __syncthreads();
        *(int4*)&Asm[r][kc]     = *(const int4*)asrc;
        *(int4*)&Asm[r][kc + 8] = *(const int4*)(asrc + 8);
        *(int4*)&Bsm[r][kc]     = *(const int4*)(bg + col);
        *(int4*)&Bsm[r][kc + 8] = *(const int4*)(bg + col + 8);
        __syncthreads();
        bf16x8 af[4], bf[4];
        #pragma unroll
        for (int mt = 0; mt < 4; mt++)
            af[mt] = *(const bf16x8*)&Asm[wr * 64 + mt * 16 + (lane & 15)][(lane >> 4) * 8];
        #pragma unroll
        for (int nt = 0; nt < 4; nt++)
            bf[nt] = *(const bf16x8*)&Bsm[wc * 64 + nt * 16 + (lane & 15)][(lane >> 4) * 8];
        #pragma unroll
        for (int mt = 0; mt < 4; mt++)
            #pragma unroll
            for (int nt = 0; nt < 4; nt++)
                acc[mt][nt] = __builtin_amdgcn_mfma_f32_16x16x32_bf16(
                    af[mt], bf[nt], acc[mt][nt], 0, 0, 0);
    }
    #pragma unroll
    for (int mt = 0; mt < 4; mt++) {
        #pragma unroll
        for (int nt = 0; nt < 4; nt++) {
            int col = bn * 128 + wc * 64 + nt * 16 + (lane & 15);
            float bv = bias[col];
            #pragma unroll
            for (int rr = 0; rr < 4; rr++) {
                int row = bm * 128 + wr * 64 + mt * 16 + (lane >> 4) * 4 + rr;
                C[(size_t)row * N + col] = f2bf(acc[mt][nt][rr] + bv);
            }
        }
    }
}

// ------------------------------- LSTM scan ---------------------------------
// Persistent kernel: 32 wgs x 1024 threads (16 waves), all co-resident.
// wg = (bmg 0..3: 16-batch group, ug 0..7: 64-unit group).
// Wave w: gate gw = w>>2, unit sub-tile us = w&3 (16 units). W_hh fragments
// live in 64 VGPRs/wave. h exchanged via global bf16 double buffer with
// AGENT-scope atomics. Sync: per-wg release-store flag (own slot, no RMW),
// waiters poll 8 relaxed loads; group flag sets on separate 64B lines.
__global__ __launch_bounds__(1024, 4) void lstm_scan(
    const u16* __restrict__ xg,     // (B,T,G) bf16
    const float* __restrict__ Whh,  // (G,H) fp32
    const float* __restrict__ h0, const float* __restrict__ c0,   // (B,H)
    u16* __restrict__ hout,         // (B,T,H) bf16
    u16* hx,                        // (2,B,H) bf16 double buffer
    int* flags)                     // (4 groups x 16-int line), zeroed
{
    __shared__ u16 hl[16][520];         // 16x512 h tile, padded stride
    __shared__ float glds[4][16][68];   // [gate][batch][unit]
    const int tid = threadIdx.x, lane = tid & 63, wave = tid >> 6;
    const int wg = blockIdx.x, bmg = wg >> 3, ug = wg & 7;
    const int gw = wave >> 2, us = wave & 3;

    // Preload W_hh B-fragments: gate gw, unit col = ug*64+us*16+(lane&15),
    // k-chunk base = (lane>>4)*8; 16 chunks of K=32.
    bf16x8 breg[16];
    {
        const float* wr0 = Whh
            + (size_t)(gw * H_ + ug * 64 + us * 16 + (lane & 15)) * H_
            + ((lane >> 4) * 8);
        #pragma unroll
        for (int kk = 0; kk < 16; kk++) {
            float4 v0 = *(const float4*)(wr0 + kk * 32);
            float4 v1 = *(const float4*)(wr0 + kk * 32 + 4);
            bf16x8 bb;
            bb[0] = (short)f2bf(v0.x); bb[1] = (short)f2bf(v0.y);
            bb[2] = (short)f2bf(v0.z); bb[3] = (short)f2bf(v0.w);
            bb[4] = (short)f2bf(v1.x); bb[5] = (short)f2bf(v1.y);
            bb[6] = (short)f2bf(v1.z); bb[7] = (short)f2bf(v1.w);
            breg[kk] = bb;
        }
    }

    const int bb_ = tid >> 6, uu = tid & 63;      // batch row, unit in group
    const int brow = bmg * 16 + bb_, ucol = ug * 64 + uu;
    int* const flg = flags + bmg * 16;            // my group's 8 flag slots
    float c = c0[brow * H_ + ucol];
    {   // publish h0 slice into buffer 0 (packed u32, agent atomics)
        u32 me = f2bf(h0[brow * H_ + ucol]);
        u32 ot = (u32)__shfl_xor((int)me, 1);
        if (!(uu & 1))
            __hip_atomic_store((u32*)(hx + (size_t)brow * H_ + ucol), me | (ot << 16),
                               __ATOMIC_RELAXED, __HIP_MEMORY_SCOPE_AGENT);
    }
    __syncthreads();
    if (tid == 0)
        __hip_atomic_store(&flg[ug], 1, __ATOMIC_RELEASE, __HIP_MEMORY_SCOPE_AGENT);

    bool gaveup = false;
    #pragma unroll 1
    for (int t = 0; t < T_; ++t) {
        // prefetch this step's gate pre-activations (independent of h_t):
        // loads stay in flight through the spin-wait below.
        const size_t xb = ((size_t)brow * T_ + t) * G_ + ucol;
        u16 xi = xg[xb], xf = xg[xb + 512], xgg = xg[xb + 1024], xo = xg[xb + 1536];

        // wait: all 8 wgs of my batch group published h_t
        if (tid == 0 && !gaveup) {
            const int target = t + 1;
            int it = 0;
            for (;;) {
                int mn = 0x7fffffff;
                #pragma unroll
                for (int j = 0; j < 8; j++) {
                    int f = __hip_atomic_load(&flg[j], __ATOMIC_RELAXED,
                                              __HIP_MEMORY_SCOPE_AGENT);
                    mn = min(mn, f);
                }
                if (mn >= target) break;
                __builtin_amdgcn_s_sleep(2);
                if (++it > (1 << 20)) { gaveup = true; break; }  // never wedge
            }
            // one acquire load to pair with producers' release stores
            (void)__hip_atomic_load(&flg[0], __ATOMIC_ACQUIRE,
                                    __HIP_MEMORY_SCOPE_AGENT);
        }
        __syncthreads();

        // cooperative load of the 16x512 h_t tile into LDS (agent atomics)
        const u16* hsrc = hx + (size_t)(t & 1) * (B_ * H_) + (size_t)bmg * 16 * H_;
        {
            int i0 = tid, i1 = tid + 1024;        // u64 slots, 128 per row
            u64 v0 = __hip_atomic_load((u64*)(hsrc + (size_t)(i0 >> 7) * H_ + (i0 & 127) * 4),
                                       __ATOMIC_RELAXED, __HIP_MEMORY_SCOPE_AGENT);
            u64 v1 = __hip_atomic_load((u64*)(hsrc + (size_t)(i1 >> 7) * H_ + (i1 & 127) * 4),
                                       __ATOMIC_RELAXED, __HIP_MEMORY_SCOPE_AGENT);
            *(u64*)&hl[i0 >> 7][(i0 & 127) * 4] = v0;
            *(u64*)&hl[i1 >> 7][(i1 & 127) * 4] = v1;
        }
        __syncthreads();

        // gates = h_t @ Whh^T (this wave's 16x16 gate-unit tile), 2 accs
        f32x4 acc0 = {0.f,0.f,0.f,0.f}, acc1 = {0.f,0.f,0.f,0.f};
        const int ar = lane & 15, ac = (lane >> 4) * 8;
        #pragma unroll
        for (int kk = 0; kk < 16; kk += 2) {
            bf16x8 a0 = *(const bf16x8*)&hl[ar][ac + kk * 32];
            bf16x8 a1 = *(const bf16x8*)&hl[ar][ac + (kk + 1) * 32];
            acc0 = __builtin_amdgcn_mfma_f32_16x16x32_bf16(a0, breg[kk],     acc0, 0, 0, 0);
            acc1 = __builtin_amdgcn_mfma_f32_16x16x32_bf16(a1, breg[kk + 1], acc1, 0, 0, 0);
        }
        #pragma unroll
        for (int rr = 0; rr < 4; rr++)
            glds[gw][(lane >> 4) * 4 + rr][us * 16 + (lane & 15)] = acc0[rr] + acc1[rr];
        __syncthreads();

        // elementwise cell update; thread owns (batch bb_, unit uu)
        float ip = glds[0][bb_][uu] + bf2f(xi);
        float fp = glds[1][bb_][uu] + bf2f(xf);
        float gp = glds[2][bb_][uu] + bf2f(xgg);
        float op = glds[3][bb_][uu] + bf2f(xo);
        float gi = sigm(ip), gf = sigm(fp), gc = tanh_f(gp), go = sigm(op);
        c = gf * c + gi * gc;
        float h = go * tanh_f(c);
        u32 me = f2bf(h);
        u32 ot = (u32)__shfl_xor((int)me, 1);
        if (!(uu & 1))
            __hip_atomic_store((u32*)(hx + (size_t)((t + 1) & 1) * (B_ * H_)
                                      + (size_t)brow * H_ + ucol),
                               me | (ot << 16),
                               __ATOMIC_RELAXED, __HIP_MEMORY_SCOPE_AGENT);
        hout[((size_t)brow * T_ + t) * H_ + ucol] = (u16)me;
        __syncthreads();   // drains all threads' stores (vmcnt 0) pre-release
        if (tid == 0)
            __hip_atomic_store(&flg[ug], t + 2, __ATOMIC_RELEASE,
                               __HIP_MEMORY_SCOPE_AGENT);
    }
}

// --------------------------- FC + log_softmax ------------------------------
// Block = 256 thr = 4 waves, 16 rows/block (same b). Stage [h2[r],h2[fr]]
// rows in LDS; lane o computes logit o; wave-shfl max/sum for log_softmax.
__global__ __launch_bounds__(256) void fc_logsoftmax(
    const u16* __restrict__ h2, const u16* __restrict__ Wfcb,
    const float* __restrict__ bfc, float* __restrict__ out)
{
    __shared__ u16 hl[16][1032];
    const int tid = threadIdx.x, lane = tid & 63, wave = tid >> 6;
    const int r0 = blockIdx.x * 16;
    const int b = r0 >> 8;
    const int fr0 = (63 - b) * T_ + (r0 & 255);
    #pragma unroll
    for (int j = 0; j < 16; ++j) {
        int idx = tid + j * 256;            // 0..4095 u64 slots
        int row = idx >> 8, c4 = idx & 255; // 256 u64 per row
        const u16* src = (c4 < 128)
            ? h2 + (size_t)(r0 + row) * H_ + c4 * 4
            : h2 + (size_t)(fr0 + row) * H_ + (c4 - 128) * 4;
        *(u64*)&hl[row][c4 * 4] = *(const u64*)src;
    }
    __syncthreads();
    for (int rr = wave * 4; rr < wave * 4 + 4; ++rr) {
        float acc = -1e30f;
        if (lane < O_) {
            const u16* w = Wfcb + (size_t)lane * 1024;
            float s = 0.f;
            for (int k = 0; k < 1024; k += 8) {
                bf16x8 wv = *(const bf16x8*)(w + k);
                bf16x8 hv = *(const bf16x8*)&hl[rr][k];   // broadcast read
                #pragma unroll
                for (int e = 0; e < 8; e++)
                    s += bf2f((u16)hv[e]) * bf2f((u16)wv[e]);
            }
            acc = s + bfc[lane];
        }
        float m = acc;
        #pragma unroll
        for (int off = 32; off > 0; off >>= 1) m = fmaxf(m, __shfl_xor(m, off));
        float e = (lane < O_) ? __expf(acc - m) : 0.f;
        float sm = e;
        #pragma unroll
        for (int off = 32; off > 0; off >>= 1) sm += __shfl_xor(sm, off);
        float lse = m + __logf(sm);
        if (lane < O_) out[(size_t)(r0 + rr) * O_ + lane] = acc - lse;
    }
}

// ------------------------------ launcher -----------------------------------

extern "C" void kernel_launch(void* const* d_in, const int* in_sizes, int n_in,
                              void* d_out, int out_size, void* d_ws, size_t ws_size,
                              hipStream_t stream)
{
    (void)in_sizes; (void)n_in; (void)out_size;
    const int*   x    = (const int*)  d_in[0];
    const float* emb  = (const float*)d_in[1];
    const float* Wih1 = (const float*)d_in[2];
    const float* Whh1 = (const float*)d_in[3];
    const float* b1   = (const float*)d_in[4];
    const float* h01  = (const float*)d_in[5];
    const float* c01  = (const float*)d_in[6];
    const float* Wih2 = (const float*)d_in[7];
    const float* Whh2 = (const float*)d_in[8];
    const float* b2   = (const float*)d_in[9];
    const float* h02  = (const float*)d_in[10];
    const float* c02  = (const float*)d_in[11];
    const float* Wfc  = (const float*)d_in[12];
    const float* bfc  = (const float*)d_in[13];
    float* out = (float*)d_out;

    char* ws = (char*)d_ws;
    size_t off = 0;
    auto alloc = [&](size_t bytes) {
        char* p = ws + off; off += (bytes + 255) & ~(size_t)255; return p;
    };
    u16* A1   = (u16*)alloc((size_t)NROW * E_ * 2);     //  8.39 MB
    u16* Wb1  = (u16*)alloc((size_t)G_ * E_ * 2);       //  1.05 MB
    u16* Wb2  = (u16*)alloc((size_t)G_ * 1024 * 2);     //  4.19 MB
    u16* Wfcb = (u16*)alloc((size_t)O_ * 1024 * 2);     //  0.10 MB
    u16* xgb  = (u16*)alloc((size_t)NROW * G_ * 2);     // 67.11 MB (L1+L2 share)
    u16* h1b  = (u16*)alloc((size_t)NROW * H_ * 2);     // 16.78 MB
    u16* h2b  = (u16*)alloc((size_t)NROW * H_ * 2);     // 16.78 MB
    u16* hx   = (u16*)alloc((size_t)2 * B_ * H_ * 2);   //  0.13 MB
    int* flags= (int*)alloc((size_t)2 * 4 * 16 * sizeof(int)); // 2 layers x 4 grp
    if (off > ws_size) return;   // clean diagnostic failure, never OOB

    hipMemsetAsync(flags, 0, 2 * 4 * 16 * sizeof(int), stream);
    f32_to_bf16_vec<<<(G_ * E_ / 4 + 255) / 256, 256, 0, stream>>>(Wih1, Wb1, G_ * E_ / 4);
    f32_to_bf16_vec<<<(G_ * 1024 / 4 + 255) / 256, 256, 0, stream>>>(Wih2, Wb2, G_ * 1024 / 4);
    f32_to_bf16_vec<<<(O_ * 1024 / 4 + 255) / 256, 256, 0, stream>>>(Wfc, Wfcb, O_ * 1024 / 4);
    embed_to_bf16<<<NROW * E_ / 4 / 256, 256, 0, stream>>>(x, emb, A1);

    gemm_bf16<false><<<dim3(G_ / 128, NROW / 128), 256, 0, stream>>>(
        A1, Wb1, b1, xgb, NROW, G_, E_);
    lstm_scan<<<32, 1024, 0, stream>>>(xgb, Whh1, h01, c01, h1b, hx, flags);

    gemm_bf16<true><<<dim3(G_ / 128, NROW / 128), 256, 0, stream>>>(
        h1b, Wb2, b2, xgb, NROW, G_, 1024);
    lstm_scan<<<32, 1024, 0, stream>>>(xgb, Whh2, h02, c02, h2b, hx, flags + 64);

    fc_logsoftmax<<<NROW / 16, 256, 0, stream>>>(h2b, Wfcb, bfc, out);
}